// Round 1
// baseline (4849.136 us; speedup 1.0000x reference)
//
#include <hip/hip_runtime.h>
#include <math.h>

#define EPSV 1e-5f

// ============================================================================
// Direct 3x3 conv, zero pad. 16x16 spatial tile per block, 8 out-channels/block.
// grid: (tiles, Cout_this/8, B), block 256.
// ============================================================================
__global__ __launch_bounds__(256) void conv3x3_k(
    const float* __restrict__ in, const float* __restrict__ w,
    float* __restrict__ out, int B, int Cin, int Cout_total,
    int co_off, int H, int W) {
  const int TS = 16;
  int tiles_x = W / TS;
  int tx = blockIdx.x % tiles_x, ty = blockIdx.x / tiles_x;
  int co0 = blockIdx.y * 8;
  int b = blockIdx.z;
  int h0 = ty * TS, w0 = tx * TS;
  int lw = threadIdx.x & 15, lh = threadIdx.x >> 4;
  __shared__ float tile[18][19];
  float acc[8];
#pragma unroll
  for (int i = 0; i < 8; i++) acc[i] = 0.f;
  const float* inb = in + (long)b * Cin * H * W;
  int wstride = Cin * 9;
  for (int ci = 0; ci < Cin; ci++) {
    const float* p = inb + (long)ci * H * W;
    for (int t = threadIdx.x; t < 18 * 18; t += 256) {
      int r = t / 18, c = t - r * 18;
      int hh = h0 + r - 1, ww = w0 + c - 1;
      float v = 0.f;
      if (hh >= 0 && hh < H && ww >= 0 && ww < W) v = p[hh * W + ww];
      tile[r][c] = v;
    }
    __syncthreads();
    const float* wr = w + ((long)co0 * Cin + ci) * 9;
#pragma unroll
    for (int ky = 0; ky < 3; ky++) {
#pragma unroll
      for (int kx = 0; kx < 3; kx++) {
        float v = tile[lh + ky][lw + kx];
#pragma unroll
        for (int i = 0; i < 8; i++) acc[i] += v * wr[i * wstride + ky * 3 + kx];
      }
    }
    __syncthreads();
  }
  long hw = (long)H * W;
  long obase = (((long)b * Cout_total + co_off + co0) * H + h0 + lh) * W + w0 + lw;
#pragma unroll
  for (int i = 0; i < 8; i++) out[obase + (long)i * hw] = acc[i];
}

// ============================================================================
// align-corners bilinear resize (B=4 fixed)
// ============================================================================
__global__ void resize_k(const float* __restrict__ in, float* __restrict__ out,
                         int C, int H, int W, int Ho, int Wo, float sy, float sx) {
  long idx = ((long)blockIdx.x << 8) + threadIdx.x;
  long total = (long)4 * C * Ho * Wo;
  if (idx >= total) return;
  int wo = (int)(idx % Wo); long t = idx / Wo;
  int ho = (int)(t % Ho); t /= Ho; // t = b*C+c
  float ys = ho * sy, xs = wo * sx;
  int y0 = (int)ys, x0 = (int)xs;
  float wy = ys - y0, wx = xs - x0;
  int y1 = min(y0 + 1, H - 1), x1 = min(x0 + 1, W - 1);
  const float* p = in + t * H * W;
  float v00 = p[y0 * W + x0], v01 = p[y0 * W + x1];
  float v10 = p[y1 * W + x0], v11 = p[y1 * W + x1];
  float r0 = v00 * (1.f - wx) + v01 * wx;
  float r1 = v10 * (1.f - wx) + v11 * wx;
  out[idx] = r0 * (1.f - wy) + r1 * wy;
}

// ============================================================================
// stats: partial sums (sum, sumsq) via atomics, then finalize mean/rstd
// ============================================================================
__global__ void gn_sums_k(const float* __restrict__ x, float* __restrict__ sums,
                          int Ctot, int coff, int cpg, int HW, int Gn) {
  int bg = blockIdx.x; int b = bg / Gn, g = bg % Gn;
  const float* p = x + ((long)b * Ctot + coff + (long)g * cpg) * HW;
  long len = (long)cpg * HW;
  long chunk = len / gridDim.y;
  long s = (long)blockIdx.y * chunk, e = s + chunk;
  float s0 = 0.f, s1 = 0.f;
  for (long i = s + threadIdx.x; i < e; i += 256) {
    float v = p[i]; s0 += v; s1 += v * v;
  }
  __shared__ float r0[256], r1[256];
  int t = threadIdx.x;
  r0[t] = s0; r1[t] = s1;
  __syncthreads();
  for (int off = 128; off > 0; off >>= 1) {
    if (t < off) { r0[t] += r0[t + off]; r1[t] += r1[t + off]; }
    __syncthreads();
  }
  if (t == 0) { atomicAdd(&sums[2 * bg], r0[0]); atomicAdd(&sums[2 * bg + 1], r1[0]); }
}

__global__ void bn_sums_k(const float* __restrict__ x, float* __restrict__ sums, int C) {
  int c = blockIdx.x;
  long total = 4L << 14;
  long chunk = total / gridDim.y;
  long s = (long)blockIdx.y * chunk, e = s + chunk;
  float s0 = 0.f, s1 = 0.f;
  for (long i = s + threadIdx.x; i < e; i += 256) {
    int b = (int)(i >> 14); int hw = (int)(i & 16383);
    float v = x[(((long)b * C + c) << 14) + hw];
    s0 += v; s1 += v * v;
  }
  __shared__ float r0[256], r1[256];
  int t = threadIdx.x;
  r0[t] = s0; r1[t] = s1;
  __syncthreads();
  for (int off = 128; off > 0; off >>= 1) {
    if (t < off) { r0[t] += r0[t + off]; r1[t] += r1[t + off]; }
    __syncthreads();
  }
  if (t == 0) { atomicAdd(&sums[2 * c], r0[0]); atomicAdd(&sums[2 * c + 1], r1[0]); }
}

__global__ void stats_fin_k(const float* __restrict__ sums, float* __restrict__ mean,
                            float* __restrict__ rstd, int n, float inv_count) {
  int i = threadIdx.x;
  if (i >= n) return;
  float m = sums[2 * i] * inv_count;
  float v = sums[2 * i + 1] * inv_count - m * m;
  mean[i] = m;
  rstd[i] = rsqrtf(fmaxf(v, 0.f) + EPSV);
}

// ============================================================================
// IDWT(haar) fused with GN+tanh+scale of det conv output
// det: [4][128][64][64] (ch 0..31 = ll via gn_ll, 32..127 = high via gn_high)
// rec: [4][32][128][128]
// ============================================================================
__global__ void idwt_k(const float* __restrict__ det,
                       const float* __restrict__ mll, const float* __restrict__ rll,
                       const float* __restrict__ gll, const float* __restrict__ bll,
                       const float* __restrict__ mhi, const float* __restrict__ rhi,
                       const float* __restrict__ ghi, const float* __restrict__ bhi,
                       const float* __restrict__ wsc, float* __restrict__ rec) {
  long idx = ((long)blockIdx.x << 8) + threadIdx.x;
  if (idx >= (long)4 * 32 * 64 * 64) return;
  int j = (int)(idx & 63); long t = idx >> 6;
  int i = (int)(t & 63); t >>= 6;
  int c = (int)(t & 31); int b = (int)(t >> 5);
  float s = wsc[0]; s = fminf(fmaxf(s, 1.f), 5.f);
  const float* dp = det + ((long)b << 19);
  long sp = ((long)i << 6) + j;
  int sidx = b * 8 + (c >> 2);
  float ll = tanhf((dp[((long)c << 12) + sp] - mll[sidx]) * rll[sidx] * gll[c] + bll[c]) * s;
  int hc = c; sidx = b * 8 + hc / 12;
  float lh = tanhf((dp[((long)(32 + hc) << 12) + sp] - mhi[sidx]) * rhi[sidx] * ghi[hc] + bhi[hc]) * s;
  hc = 32 + c; sidx = b * 8 + hc / 12;
  float hl = tanhf((dp[((long)(32 + hc) << 12) + sp] - mhi[sidx]) * rhi[sidx] * ghi[hc] + bhi[hc]) * s;
  hc = 64 + c; sidx = b * 8 + hc / 12;
  float hh = tanhf((dp[((long)(32 + hc) << 12) + sp] - mhi[sidx]) * rhi[sidx] * ghi[hc] + bhi[hc]) * s;
  float x00 = (ll + lh + hl + hh) * 0.5f;
  float x01 = (ll - lh + hl - hh) * 0.5f;
  float x10 = (ll + lh - hl - hh) * 0.5f;
  float x11 = (ll - lh - hl + hh) * 0.5f;
  float* rp = rec + (((long)b * 32 + c) << 14) + ((long)i << 8) + (j << 1);
  rp[0] = x00; rp[1] = x01; rp[128] = x10; rp[129] = x11;
}

// ============================================================================
// skip_up_raw = W_adj (128x32) @ rec. grid (64, 8, 4), block 256.
// ============================================================================
__global__ __launch_bounds__(256) void adj_k(const float* __restrict__ rec,
                                             const float* __restrict__ Wadj,
                                             float* __restrict__ out) {
  __shared__ float ls[32][256];
  int n0 = blockIdx.x << 8;
  int o0 = blockIdx.y << 4;
  int b = blockIdx.z;
  int t = threadIdx.x;
  for (int idx = t; idx < 32 * 256; idx += 256) {
    int c = idx >> 8, n = idx & 255;
    ls[c][n] = rec[(((long)b * 32 + c) << 14) + n0 + n];
  }
  __syncthreads();
  float acc[16];
#pragma unroll
  for (int i = 0; i < 16; i++) acc[i] = 0.f;
  for (int c = 0; c < 32; c++) {
    float v = ls[c][t];
#pragma unroll
    for (int i = 0; i < 16; i++) acc[i] += v * Wadj[(o0 + i) * 32 + c];
  }
#pragma unroll
  for (int i = 0; i < 16; i++)
    out[(((long)b * 128 + o0 + i) << 14) + n0 + t] = acc[i];
}

// ============================================================================
// GN apply (C=128, G=8, HW=16384, B=4) in place.
// mode 0: plain, 1: relu, 2: silu then += add (att_in = merged + silu(gn(x)))
// ============================================================================
__global__ void gn_apply_k(float* __restrict__ x, const float* __restrict__ mean,
                           const float* __restrict__ rstd, const float* __restrict__ gamma,
                           const float* __restrict__ beta, const float* __restrict__ add,
                           int mode) {
  long idx = ((long)blockIdx.x << 8) + threadIdx.x;
  int ch = (int)((idx >> 14) & 127);
  int b = (int)(idx >> 21);
  int s = b * 8 + (ch >> 4);
  float v = (x[idx] - mean[s]) * rstd[s] * gamma[ch] + beta[ch];
  if (mode == 1) v = fmaxf(v, 0.f);
  else if (mode == 2) { v = v / (1.f + expf(-v)); v += add[idx]; }
  x[idx] = v;
}

// BN apply + relu (+ optional add), in place. C=128, HW=16384.
__global__ void bn_apply_k(float* __restrict__ x, const float* __restrict__ mean,
                           const float* __restrict__ rstd, const float* __restrict__ gamma,
                           const float* __restrict__ beta, const float* __restrict__ add) {
  long idx = ((long)blockIdx.x << 8) + threadIdx.x;
  int ch = (int)((idx >> 14) & 127);
  float v = fmaxf((x[idx] - mean[ch]) * rstd[ch] * gamma[ch] + beta[ch], 0.f);
  if (add) v += add[idx];
  x[idx] = v;
}

// ============================================================================
// column sum over N=16384: S[bc] = sum_n x[bc][n]; grid B*C blocks
// ============================================================================
__global__ void colsum_k(const float* __restrict__ x, float* __restrict__ S) {
  int bc = blockIdx.x;
  const float* p = x + ((long)bc << 14);
  float a = 0.f;
  for (int i = threadIdx.x; i < 16384; i += 256) a += p[i];
  __shared__ float red[256];
  red[threadIdx.x] = a;
  __syncthreads();
  for (int off = 128; off > 0; off >>= 1) {
    if (threadIdx.x < off) red[threadIdx.x] += red[threadIdx.x + off];
    __syncthreads();
  }
  if (threadIdx.x == 0) S[bc] = red[0];
}

// ============================================================================
// Gram: G[p,b,c,c'] = sum_n merged[b,c,n]*feats[p][b,c',n], split over n.
// grid (32, 3, 4), block 256, 8x8 accumulators per thread, atomicAdd epilogue.
// ============================================================================
__global__ __launch_bounds__(256) void gram_k(const float* __restrict__ merged,
                                              const float* __restrict__ f0,
                                              const float* __restrict__ f1,
                                              const float* __restrict__ f2,
                                              float* __restrict__ G) {
  int p = blockIdx.y, b = blockIdx.z;
  const float* fp = (p == 0) ? f0 : ((p == 1) ? f1 : f2);
  const float* mb = merged + ((long)b << 21);
  const float* fb = fp + ((long)b << 21);
  int n0 = blockIdx.x << 9;
  __shared__ float Am[128][17], Bm[128][17];
  int t = threadIdx.x;
  int tc = t >> 4, tcp = t & 15;
  float acc[8][8];
#pragma unroll
  for (int i = 0; i < 8; i++)
#pragma unroll
    for (int j = 0; j < 8; j++) acc[i][j] = 0.f;
  for (int ks = 0; ks < 32; ks++) {
    int nb = n0 + (ks << 4);
    for (int idx = t; idx < 2048; idx += 256) {
      int c = idx >> 4, k = idx & 15;
      Am[c][k] = mb[((long)c << 14) + nb + k];
      Bm[c][k] = fb[((long)c << 14) + nb + k];
    }
    __syncthreads();
    for (int k = 0; k < 16; k++) {
      float av[8], bv2[8];
#pragma unroll
      for (int i = 0; i < 8; i++) av[i] = Am[tc * 8 + i][k];
#pragma unroll
      for (int j = 0; j < 8; j++) bv2[j] = Bm[tcp * 8 + j][k];
#pragma unroll
      for (int i = 0; i < 8; i++)
#pragma unroll
        for (int j = 0; j < 8; j++) acc[i][j] += av[i] * bv2[j];
    }
    __syncthreads();
  }
  float* Gp = G + ((long)(p * 4 + b) << 14);
#pragma unroll
  for (int i = 0; i < 8; i++)
#pragma unroll
    for (int j = 0; j < 8; j++)
      atomicAdd(&Gp[(tc * 8 + i) * 128 + tcp * 8 + j], acc[i][j]);
}

// ============================================================================
// attention logits from Gram + softmax.
// logits = Wq G Wk^T + bq*(Wk.S1) + bk*(Wq.S2) + N*bq*bk, scaled 1/sqrt(32).
// grid (h=4, b=4, p=3), block 256.
// ============================================================================
__global__ __launch_bounds__(256) void attn_k(const float* __restrict__ G,
                                              const float* __restrict__ S1,
                                              const float* __restrict__ S2,
                                              const float* __restrict__ Wq,
                                              const float* __restrict__ bq,
                                              const float* __restrict__ Wk,
                                              const float* __restrict__ bk,
                                              float* __restrict__ attn) {
  int h = blockIdx.x, b = blockIdx.y, p = blockIdx.z;
  __shared__ float T[32][129];
  __shared__ float QS2[32], KS1[32];
  __shared__ float L[32][33];
  const float* Gpb = G + ((long)(p * 4 + b) << 14);
  const float* Wqp = Wq + p * 16384;
  const float* Wkp = Wk + p * 16384;
  int t = threadIdx.x;
  if (t < 32) {
    float a = 0.f;
    for (int c = 0; c < 128; c++) a += Wqp[(h * 32 + t) * 128 + c] * S2[b * 128 + c];
    QS2[t] = a;
  } else if (t < 64) {
    int e = t - 32;
    float a = 0.f;
    for (int c = 0; c < 128; c++) a += Wkp[(h * 32 + e) * 128 + c] * S1[(p * 4 + b) * 128 + c];
    KS1[e] = a;
  }
  __syncthreads();
  for (int ii = t; ii < 4096; ii += 256) {
    int d = ii >> 7, cp = ii & 127;
    float a = 0.f;
    for (int c = 0; c < 128; c++) a += Wqp[(h * 32 + d) * 128 + c] * Gpb[c * 128 + cp];
    T[d][cp] = a;
  }
  __syncthreads();
  const float scale = 0.17677669529663687f; // 1/sqrt(32)
  for (int ii = t; ii < 1024; ii += 256) {
    int d = ii >> 5, e = ii & 31;
    float a = 0.f;
    for (int cp = 0; cp < 128; cp++) a += T[d][cp] * Wkp[(h * 32 + e) * 128 + cp];
    float bqv = bq[p * 128 + h * 32 + d], bkv = bk[p * 128 + h * 32 + e];
    a += bqv * KS1[e] + bkv * QS2[d] + 16384.f * bqv * bkv;
    L[d][e] = a * scale;
  }
  __syncthreads();
  if (t < 32) {
    float mx = -1e30f;
    for (int e = 0; e < 32; e++) mx = fmaxf(mx, L[t][e]);
    float sum = 0.f;
    for (int e = 0; e < 32; e++) { float ev = expf(L[t][e] - mx); L[t][e] = ev; sum += ev; }
    float inv = 1.f / sum;
    float* ap = attn + ((((long)(p * 4 + b)) * 4 + h) * 32 + t) * 32;
    for (int e = 0; e < 32; e++) ap[e] = L[t][e] * inv;
  }
}

// ============================================================================
// M[p,b,o,a'] = sum_d W_fuse[o, p*128 + h*32 + d] * attn[p,b,h,d,e], a'=h*32+e
// also cbias[b,o] += sum_{a'} M * bv[p,a'].  grid (o=128, b=4, p=3), block 128.
// ============================================================================
__global__ void m_k(const float* __restrict__ Wf, const float* __restrict__ attn,
                    const float* __restrict__ bv, float* __restrict__ M,
                    float* __restrict__ cbias) {
  int o = blockIdx.x, b = blockIdx.y, p = blockIdx.z;
  int ap = threadIdx.x;
  int h = ap >> 5, e = ap & 31;
  const float* at = attn + (((long)(p * 4 + b)) * 4 + h) * 1024;
  const float* wrow = Wf + o * 384 + p * 128 + h * 32;
  float acc = 0.f;
  for (int d = 0; d < 32; d++) acc += wrow[d] * at[d * 32 + e];
  M[(((long)(p * 4 + b)) * 128 + o) * 128 + ap] = acc;
  __shared__ float red[128];
  red[ap] = acc * bv[p * 128 + ap];
  __syncthreads();
  for (int off = 64; off > 0; off >>= 1) {
    if (ap < off) red[ap] += red[ap + off];
    __syncthreads();
  }
  if (ap == 0) atomicAdd(&cbias[b * 128 + o], red[0]);
}

// Weff[b,o,p,c] = sum_{a'} M[p,b,o,a'] * Wv[p,a',c]. grid (o,b,p), block 128.
__global__ void weff_k(const float* __restrict__ M, const float* __restrict__ Wv,
                       float* __restrict__ Weff) {
  int o = blockIdx.x, b = blockIdx.y, p = blockIdx.z, c = threadIdx.x;
  const float* mrow = M + (((long)(p * 4 + b)) * 128 + o) * 128;
  const float* wv = Wv + p * 16384;
  float acc = 0.f;
  for (int a = 0; a < 128; a++) acc += mrow[a] * wv[a * 128 + c];
  Weff[(((long)b * 128 + o) * 3 + p) * 128 + c] = acc;
}

// ============================================================================
// fused_pre[b,o,n] = sum_{k<384} Weff[b,o,k] * feats[k/128][b,k%128,n]
//                    + b_fuse[o] + cbias[b,o]
// grid (n tiles 256, o tiles 2, b 4), block 256, 64x64 tile, 4x4 micro.
// ============================================================================
__global__ __launch_bounds__(256) void fuse_gemm_k(const float* __restrict__ Weff,
                                                   const float* __restrict__ f0,
                                                   const float* __restrict__ f1,
                                                   const float* __restrict__ f2,
                                                   const float* __restrict__ bf,
                                                   const float* __restrict__ cbias,
                                                   float* __restrict__ out) {
  int b = blockIdx.z;
  int o0 = blockIdx.y * 64;
  int n0 = blockIdx.x * 64;
  __shared__ float As[16][65], Bs[16][65];
  int t = threadIdx.x;
  int tn = t & 15, to = t >> 4;
  float acc[4][4];
#pragma unroll
  for (int i = 0; i < 4; i++)
#pragma unroll
    for (int j = 0; j < 4; j++) acc[i][j] = 0.f;
  for (int k0 = 0; k0 < 384; k0 += 16) {
    for (int idx = t; idx < 1024; idx += 256) {
      int o = idx >> 4, k = idx & 15;
      As[k][o] = Weff[((long)(b * 128 + o0 + o)) * 384 + k0 + k];
    }
    for (int idx = t; idx < 1024; idx += 256) {
      int k = idx >> 6, n = idx & 63;
      int c = k0 + k;
      const float* f = (c < 128) ? f0 : ((c < 256) ? f1 : f2);
      int cc = c & 127;
      Bs[k][n] = f[(((long)b * 128 + cc) << 14) + n0 + n];
    }
    __syncthreads();
    for (int k = 0; k < 16; k++) {
      float av[4], bvv[4];
#pragma unroll
      for (int i = 0; i < 4; i++) av[i] = As[k][to * 4 + i];
#pragma unroll
      for (int j = 0; j < 4; j++) bvv[j] = Bs[k][tn * 4 + j];
#pragma unroll
      for (int i = 0; i < 4; i++)
#pragma unroll
        for (int j = 0; j < 4; j++) acc[i][j] += av[i] * bvv[j];
    }
    __syncthreads();
  }
#pragma unroll
  for (int i = 0; i < 4; i++) {
    int o = o0 + to * 4 + i;
    float bias = bf[o] + cbias[b * 128 + o];
#pragma unroll
    for (int j = 0; j < 4; j++)
      out[(((long)b * 128 + o) << 14) + n0 + tn * 4 + j] = acc[i][j] + bias;
  }
}

// ============================================================================
extern "C" void kernel_launch(void* const* d_in, const int* in_sizes, int n_in,
                              void* d_out, int out_size, void* d_ws, size_t ws_size,
                              hipStream_t stream) {
  const float* x      = (const float*)d_in[0];
  const float* sdet   = (const float*)d_in[1];
  const float* sstru  = (const float*)d_in[2];
  const float* sglob  = (const float*)d_in[3];
  const float* W_up   = (const float*)d_in[4];
  const float* bnug   = (const float*)d_in[5];
  const float* bnub   = (const float*)d_in[6];
  const float* W_ll   = (const float*)d_in[7];
  const float* gllg   = (const float*)d_in[8];
  const float* gllb   = (const float*)d_in[9];
  const float* W_hi   = (const float*)d_in[10];
  const float* ghig   = (const float*)d_in[11];
  const float* ghib   = (const float*)d_in[12];
  const float* wsc    = (const float*)d_in[13];
  const float* W_adj  = (const float*)d_in[14];
  const float* gadjg  = (const float*)d_in[15];
  const float* gadjb  = (const float*)d_in[16];
  const float* Wq     = (const float*)d_in[17];
  const float* bq     = (const float*)d_in[18];
  const float* Wk     = (const float*)d_in[19];
  const float* bk     = (const float*)d_in[20];
  const float* Wv     = (const float*)d_in[21];
  const float* bv     = (const float*)d_in[22];
  const float* W_fu   = (const float*)d_in[23];
  const float* b_fu   = (const float*)d_in[24];
  const float* gfug   = (const float*)d_in[25];
  const float* gfub   = (const float*)d_in[26];
  const float* goug   = (const float*)d_in[27];
  const float* goub   = (const float*)d_in[28];
  const float* W_r1   = (const float*)d_in[29];
  const float* bn1g   = (const float*)d_in[30];
  const float* bn1b   = (const float*)d_in[31];
  const float* W_r2   = (const float*)d_in[32];
  const float* bn2g   = (const float*)d_in[33];
  const float* bn2b   = (const float*)d_in[34];
  float* out = (float*)d_out;

  float* ws = (float*)d_ws;
  size_t off = 0;
  auto alloc = [&](size_t n) { float* p = ws + off; off += n; return p; };
  float* bufA = alloc(16777216); // xu (4,256,128,128); later fused_pre/att buffer (first 8.4M)
  float* bufB = alloc(8388608);  // conv_up raw -> merged; later r1
  float* bufC = alloc(8388608);  // skip_up
  float* bufD = alloc(8388608);  // resized skip_global
  float* det  = alloc(2097152);  // (4,128,64,64)
  float* rec  = alloc(2097152);  // (4,32,128,128)
  float* Gm   = alloc(196608);
  float* S1b  = alloc(1536);
  float* S2b  = alloc(512);
  float* attb = alloc(49152);
  float* Mb   = alloc(196608);
  float* Wef  = alloc(196608);
  float* cb   = alloc(512);
  float* sums = alloc(1024);
  float* mLL = alloc(32); float* rLL = alloc(32);
  float* mHI = alloc(32); float* rHI = alloc(32);
  float* mS  = alloc(256); float* rS = alloc(256);

  const float s63 = 63.f / 127.f;

  // ---- detail branch: conv_ll + conv_high (concat into det)
  conv3x3_k<<<dim3(16, 4, 4), 256, 0, stream>>>(sdet, W_ll, det, 4, 128, 128, 0, 64, 64);
  conv3x3_k<<<dim3(16, 12, 4), 256, 0, stream>>>(sdet, W_hi, det, 4, 128, 128, 32, 64, 64);
  hipMemsetAsync(sums, 0, 64 * sizeof(float), stream);
  gn_sums_k<<<dim3(32, 4), 256, 0, stream>>>(det, sums, 128, 0, 4, 4096, 8);
  stats_fin_k<<<1, 64, 0, stream>>>(sums, mLL, rLL, 32, 1.f / 16384.f);
  hipMemsetAsync(sums, 0, 64 * sizeof(float), stream);
  gn_sums_k<<<dim3(32, 8), 256, 0, stream>>>(det, sums, 128, 32, 12, 4096, 8);
  stats_fin_k<<<1, 64, 0, stream>>>(sums, mHI, rHI, 32, 1.f / 49152.f);
  idwt_k<<<2048, 256, 0, stream>>>(det, mLL, rLL, gllg, gllb, mHI, rHI, ghig, ghib, wsc, rec);

  // ---- skip_up = relu(GN(W_adj @ rec))
  adj_k<<<dim3(64, 8, 4), 256, 0, stream>>>(rec, W_adj, bufC);
  hipMemsetAsync(sums, 0, 64 * sizeof(float), stream);
  gn_sums_k<<<dim3(32, 16), 256, 0, stream>>>(bufC, sums, 128, 0, 16, 16384, 8);
  stats_fin_k<<<1, 64, 0, stream>>>(sums, mS, rS, 32, 1.f / 262144.f);
  gn_apply_k<<<32768, 256, 0, stream>>>(bufC, mS, rS, gadjg, gadjb, nullptr, 1);

  // ---- xu = resize(x); merged = relu(BN(conv(xu))) + skip_up
  resize_k<<<65536, 256, 0, stream>>>(x, bufA, 256, 64, 64, 128, 128, s63, s63);
  conv3x3_k<<<dim3(64, 16, 4), 256, 0, stream>>>(bufA, W_up, bufB, 4, 256, 128, 0, 128, 128);
  hipMemsetAsync(sums, 0, 256 * sizeof(float), stream);
  bn_sums_k<<<dim3(128, 16), 256, 0, stream>>>(bufB, sums, 128);
  stats_fin_k<<<1, 128, 0, stream>>>(sums, mS, rS, 128, 1.f / 65536.f);
  bn_apply_k<<<32768, 256, 0, stream>>>(bufB, mS, rS, bnug, bnub, bufC);

  // ---- feats[2] = resize(skip_global)
  resize_k<<<32768, 256, 0, stream>>>(sglob, bufD, 128, 64, 64, 128, 128, s63, s63);

  // ---- attention via Gram matrices
  colsum_k<<<512, 256, 0, stream>>>(bufB, S2b);
  colsum_k<<<512, 256, 0, stream>>>(bufC, S1b);
  colsum_k<<<512, 256, 0, stream>>>(sstru, S1b + 512);
  colsum_k<<<512, 256, 0, stream>>>(bufD, S1b + 1024);
  hipMemsetAsync(Gm, 0, 196608 * sizeof(float), stream);
  gram_k<<<dim3(32, 3, 4), 256, 0, stream>>>(bufB, bufC, sstru, bufD, Gm);
  attn_k<<<dim3(4, 4, 3), 256, 0, stream>>>(Gm, S1b, S2b, Wq, bq, Wk, bk, attb);

  // ---- collapse attn@v + concat + W_fuse into per-batch 384->128 GEMM
  hipMemsetAsync(cb, 0, 512 * sizeof(float), stream);
  m_k<<<dim3(128, 4, 3), 128, 0, stream>>>(W_fu, attb, bv, Mb, cb);
  weff_k<<<dim3(128, 4, 3), 128, 0, stream>>>(Mb, Wv, Wef);
  fuse_gemm_k<<<dim3(256, 2, 4), 256, 0, stream>>>(Wef, bufC, sstru, bufD, b_fu, cb, bufA);

  // ---- fused = silu(GN(fused_pre)); att_in = merged + fused (in place bufA)
  hipMemsetAsync(sums, 0, 64 * sizeof(float), stream);
  gn_sums_k<<<dim3(32, 16), 256, 0, stream>>>(bufA, sums, 128, 0, 16, 16384, 8);
  stats_fin_k<<<1, 64, 0, stream>>>(sums, mS, rS, 32, 1.f / 262144.f);
  gn_apply_k<<<32768, 256, 0, stream>>>(bufA, mS, rS, gfug, gfub, bufB, 2);

  // ---- att_out = GN(att_in) (in place bufA)
  hipMemsetAsync(sums, 0, 64 * sizeof(float), stream);
  gn_sums_k<<<dim3(32, 16), 256, 0, stream>>>(bufA, sums, 128, 0, 16, 16384, 8);
  stats_fin_k<<<1, 64, 0, stream>>>(sums, mS, rS, 32, 1.f / 262144.f);
  gn_apply_k<<<32768, 256, 0, stream>>>(bufA, mS, rS, goug, goub, nullptr, 0);

  // ---- r1 = relu(BN(conv(att_out, W_r1)))
  conv3x3_k<<<dim3(64, 16, 4), 256, 0, stream>>>(bufA, W_r1, bufB, 4, 128, 128, 0, 128, 128);
  hipMemsetAsync(sums, 0, 256 * sizeof(float), stream);
  bn_sums_k<<<dim3(128, 16), 256, 0, stream>>>(bufB, sums, 128);
  stats_fin_k<<<1, 128, 0, stream>>>(sums, mS, rS, 128, 1.f / 65536.f);
  bn_apply_k<<<32768, 256, 0, stream>>>(bufB, mS, rS, bn1g, bn1b, nullptr);

  // ---- r2 = relu(BN(conv(r1, W_r2))) -> d_out
  conv3x3_k<<<dim3(64, 16, 4), 256, 0, stream>>>(bufB, W_r2, out, 4, 128, 128, 0, 128, 128);
  hipMemsetAsync(sums, 0, 256 * sizeof(float), stream);
  bn_sums_k<<<dim3(128, 16), 256, 0, stream>>>(out, sums, 128);
  stats_fin_k<<<1, 128, 0, stream>>>(sums, mS, rS, 128, 1.f / 65536.f);
  bn_apply_k<<<32768, 256, 0, stream>>>(out, mS, rS, bn2g, bn2b, nullptr);
}

// Round 2
// 1412.866 us; speedup vs baseline: 3.4321x; 3.4321x over previous
//
#include <hip/hip_runtime.h>
#include <math.h>

#define EPSV 1e-5f

typedef __attribute__((ext_vector_type(8))) short short8;
typedef __attribute__((ext_vector_type(4))) float f32x4;

__device__ inline unsigned short f2bf(float x) {
  unsigned int u = __float_as_uint(x);
  return (unsigned short)((u + 0x7FFFu + ((u >> 16) & 1u)) >> 16);
}

// ============================================================================
// Weight prepack: W fp32 [Cout][Cin][3][3] -> wpk bf16 [9][128][Cin]
// ============================================================================
__global__ void packw_k(const float* __restrict__ w, unsigned short* __restrict__ wpk,
                        int Cout, int Cin, int co_off) {
  int idx = blockIdx.x * 256 + threadIdx.x;
  int total = Cout * Cin * 9;
  if (idx >= total) return;
  int kk = idx % 9;
  int ci = (idx / 9) % Cin;
  int co = idx / (9 * Cin);
  wpk[((long)kk * 128 + co_off + co) * Cin + ci] = f2bf(w[idx]);
}

// ============================================================================
// Tiled NCHW fp32 -> NHWC bf16 transpose/convert. tile 32c x 64hw.
// grid (HW/64, C/32, 4), block 256.
// ============================================================================
__global__ void t_nhwc_k(const float* __restrict__ in, unsigned short* __restrict__ out,
                         int C, int HW) {
  __shared__ unsigned short lds[64][34];
  int b = blockIdx.z;
  int c0 = blockIdx.y << 5;
  int hw0 = blockIdx.x << 6;
  int t = threadIdx.x;
  int c = t >> 3, j0 = (t & 7) << 3;
  const float* p = in + ((long)b * C + c0 + c) * HW + hw0 + j0;
#pragma unroll
  for (int j = 0; j < 8; j++) lds[j0 + j][c] = f2bf(p[j]);
  __syncthreads();
  int hw = t >> 2, k = (t & 3) << 3;
  unsigned short* q = out + ((long)(b * HW + hw0 + hw)) * C + c0 + k;
  int4 val;
  unsigned short* vs = (unsigned short*)&val;
#pragma unroll
  for (int i = 0; i < 8; i++) vs[i] = lds[hw][k + i];
  *(int4*)q = val;
}

// ============================================================================
// Bilinear resize (align-corners) fp32 NCHW -> bf16 NHWC, 8 channels/thread.
// ============================================================================
__global__ void resize_bf_k(const float* __restrict__ in, unsigned short* __restrict__ out,
                            int C, int H, int W, int Ho, int Wo, float s) {
  long idx = (long)blockIdx.x * 256 + threadIdx.x;
  int nc8 = C >> 3;
  long total = (long)4 * Ho * Wo * nc8;
  if (idx >= total) return;
  int c8 = (int)(idx % nc8); long t2 = idx / nc8;
  int wo = (int)(t2 % Wo); t2 /= Wo;
  int ho = (int)(t2 % Ho); int b = (int)(t2 / Ho);
  float ys = ho * s, xs = wo * s;
  int y0 = (int)ys, x0 = (int)xs;
  float wy = ys - y0, wx = xs - x0;
  int y1 = min(y0 + 1, H - 1), x1 = min(x0 + 1, W - 1);
  const float* p = in + ((long)(b * C + c8 * 8)) * H * W;
  unsigned short* q = out + ((long)(b * Ho + ho) * Wo + wo) * C + c8 * 8;
#pragma unroll
  for (int i = 0; i < 8; i++, p += (long)H * W) {
    float v00 = p[y0 * W + x0], v01 = p[y0 * W + x1];
    float v10 = p[y1 * W + x0], v11 = p[y1 * W + x1];
    float r0 = v00 + (v01 - v00) * wx;
    float r1 = v10 + (v11 - v10) * wx;
    q[i] = f2bf(r0 + (r1 - r0) * wy);
  }
}

// ============================================================================
// MFMA implicit-GEMM 3x3 conv, zero pad.
// xin: bf16 NHWC [4][H][W_][CIN]; wpk: bf16 [9][128][CIN]; out: fp32 [4][128][H][W_]
// Block = 256 thr (4 waves), tile = 128 co x W_ n (one image row).
// Per phase (ci-chunk 32, ky): stage 3 kx weights + 1 halo'd input row into LDS,
// then 3 kx of 16x16x32 bf16 MFMA. CPAD=40 keeps ds_read_b128 16B-aligned and
// 2-way-max bank aliasing (free on CDNA4).
// ============================================================================
template <int W_, int CIN, int FC, int FN>
__global__ __launch_bounds__(256) void conv_mfma_k(
    const unsigned short* __restrict__ xin, const unsigned short* __restrict__ wpk,
    float* __restrict__ out, int H) {
  constexpr int NWN = W_ / (FN * 16);
  constexpr int CPAD = 40;
  __shared__ unsigned short w3[3 * 128 * CPAD];
  __shared__ unsigned short rowb[(W_ + 2) * CPAD];
  int h = blockIdx.x, b = blockIdx.y;
  int t = threadIdx.x;
  int wid = t >> 6, lane = t & 63;
  int co0 = (wid / NWN) * (FC * 16);
  int n0 = (wid % NWN) * (FN * 16);
  int lm = lane & 15, lk = lane >> 4;
  f32x4 acc[FC][FN];
#pragma unroll
  for (int i = 0; i < FC; i++)
#pragma unroll
    for (int j = 0; j < FN; j++) acc[i][j] = (f32x4){0.f, 0.f, 0.f, 0.f};

  for (int c0 = 0; c0 < CIN; c0 += 32) {
    for (int ky = 0; ky < 3; ky++) {
      int hr = h + ky - 1;
      __syncthreads();
      // stage weights: [3 kx][128 co][32 ci]
#pragma unroll
      for (int i = 0; i < 6; i++) {
        int e = (i * 256 + t) * 8;
        int kx = e >> 12, rem = e & 4095;
        int co = rem >> 5, ci = rem & 31;
        const unsigned short* g = wpk + ((long)((ky * 3 + kx) * 128 + co)) * CIN + c0 + ci;
        *(int4*)&w3[(kx * 128 + co) * CPAD + ci] = *(const int4*)g;
      }
      // stage input row hr, cols -1..W_, ci chunk
      constexpr int RE = (W_ + 2) * 32 / 8;
      for (int i = t; i < RE; i += 256) {
        int e = i * 8;
        int col = e >> 5, ci = e & 31;
        int gc = col - 1;
        int4 v = {0, 0, 0, 0};
        if (hr >= 0 && hr < H && gc >= 0 && gc < W_) {
          const unsigned short* g = xin + ((long)((b * H + hr) * W_ + gc)) * CIN + c0 + ci;
          v = *(const int4*)g;
        }
        *(int4*)&rowb[col * CPAD + ci] = v;
      }
      __syncthreads();
#pragma unroll
      for (int kx = 0; kx < 3; kx++) {
        short8 afr[FC], bfr[FN];
#pragma unroll
        for (int i = 0; i < FC; i++)
          afr[i] = *(const short8*)&w3[(kx * 128 + co0 + i * 16 + lm) * CPAD + lk * 8];
#pragma unroll
        for (int j = 0; j < FN; j++)
          bfr[j] = *(const short8*)&rowb[(n0 + j * 16 + lm + kx) * CPAD + lk * 8];
#pragma unroll
        for (int i = 0; i < FC; i++)
#pragma unroll
          for (int j = 0; j < FN; j++)
            acc[i][j] = __builtin_amdgcn_mfma_f32_16x16x32_bf16(afr[i], bfr[j], acc[i][j], 0, 0, 0);
      }
    }
  }
  // epilogue: D layout col=lane&15 -> n, row=(lane>>4)*4+reg -> co
  int co_base = co0 + lk * 4;
#pragma unroll
  for (int i = 0; i < FC; i++) {
    int co = co_base + i * 16;
#pragma unroll
    for (int j = 0; j < FN; j++) {
      int n = n0 + j * 16 + lm;
#pragma unroll
      for (int r = 0; r < 4; r++)
        out[(((long)(b * 128 + co + r)) * H + h) * W_ + n] = acc[i][j][r];
    }
  }
}

// ============================================================================
// align-corners bilinear resize fp32 -> fp32 NCHW (for skip_global feats path)
// ============================================================================
__global__ void resize_k(const float* __restrict__ in, float* __restrict__ out,
                         int C, int H, int W, int Ho, int Wo, float sy, float sx) {
  long idx = ((long)blockIdx.x << 8) + threadIdx.x;
  long total = (long)4 * C * Ho * Wo;
  if (idx >= total) return;
  int wo = (int)(idx % Wo); long t = idx / Wo;
  int ho = (int)(t % Ho); t /= Ho;
  float ys = ho * sy, xs = wo * sx;
  int y0 = (int)ys, x0 = (int)xs;
  float wy = ys - y0, wx = xs - x0;
  int y1 = min(y0 + 1, H - 1), x1 = min(x0 + 1, W - 1);
  const float* p = in + t * H * W;
  float v00 = p[y0 * W + x0], v01 = p[y0 * W + x1];
  float v10 = p[y1 * W + x0], v11 = p[y1 * W + x1];
  float r0 = v00 * (1.f - wx) + v01 * wx;
  float r1 = v10 * (1.f - wx) + v11 * wx;
  out[idx] = r0 * (1.f - wy) + r1 * wy;
}

// ============================================================================
// stats: partial sums (sum, sumsq) via atomics, then finalize mean/rstd
// ============================================================================
__global__ void gn_sums_k(const float* __restrict__ x, float* __restrict__ sums,
                          int Ctot, int coff, int cpg, int HW, int Gn) {
  int bg = blockIdx.x; int b = bg / Gn, g = bg % Gn;
  const float* p = x + ((long)b * Ctot + coff + (long)g * cpg) * HW;
  long len = (long)cpg * HW;
  long chunk = len / gridDim.y;
  long s = (long)blockIdx.y * chunk, e = s + chunk;
  float s0 = 0.f, s1 = 0.f;
  for (long i = s + threadIdx.x; i < e; i += 256) {
    float v = p[i]; s0 += v; s1 += v * v;
  }
  __shared__ float r0[256], r1[256];
  int t = threadIdx.x;
  r0[t] = s0; r1[t] = s1;
  __syncthreads();
  for (int off = 128; off > 0; off >>= 1) {
    if (t < off) { r0[t] += r0[t + off]; r1[t] += r1[t + off]; }
    __syncthreads();
  }
  if (t == 0) { atomicAdd(&sums[2 * bg], r0[0]); atomicAdd(&sums[2 * bg + 1], r1[0]); }
}

__global__ void bn_sums_k(const float* __restrict__ x, float* __restrict__ sums, int C) {
  int c = blockIdx.x;
  long total = 4L << 14;
  long chunk = total / gridDim.y;
  long s = (long)blockIdx.y * chunk, e = s + chunk;
  float s0 = 0.f, s1 = 0.f;
  for (long i = s + threadIdx.x; i < e; i += 256) {
    int b = (int)(i >> 14); int hw = (int)(i & 16383);
    float v = x[(((long)b * C + c) << 14) + hw];
    s0 += v; s1 += v * v;
  }
  __shared__ float r0[256], r1[256];
  int t = threadIdx.x;
  r0[t] = s0; r1[t] = s1;
  __syncthreads();
  for (int off = 128; off > 0; off >>= 1) {
    if (t < off) { r0[t] += r0[t + off]; r1[t] += r1[t + off]; }
    __syncthreads();
  }
  if (t == 0) { atomicAdd(&sums[2 * c], r0[0]); atomicAdd(&sums[2 * c + 1], r1[0]); }
}

__global__ void stats_fin_k(const float* __restrict__ sums, float* __restrict__ mean,
                            float* __restrict__ rstd, int n, float inv_count) {
  int i = threadIdx.x;
  if (i >= n) return;
  float m = sums[2 * i] * inv_count;
  float v = sums[2 * i + 1] * inv_count - m * m;
  mean[i] = m;
  rstd[i] = rsqrtf(fmaxf(v, 0.f) + EPSV);
}

// ============================================================================
// IDWT(haar) fused with GN+tanh+scale of det conv output
// ============================================================================
__global__ void idwt_k(const float* __restrict__ det,
                       const float* __restrict__ mll, const float* __restrict__ rll,
                       const float* __restrict__ gll, const float* __restrict__ bll,
                       const float* __restrict__ mhi, const float* __restrict__ rhi,
                       const float* __restrict__ ghi, const float* __restrict__ bhi,
                       const float* __restrict__ wsc, float* __restrict__ rec) {
  long idx = ((long)blockIdx.x << 8) + threadIdx.x;
  if (idx >= (long)4 * 32 * 64 * 64) return;
  int j = (int)(idx & 63); long t = idx >> 6;
  int i = (int)(t & 63); t >>= 6;
  int c = (int)(t & 31); int b = (int)(t >> 5);
  float s = wsc[0]; s = fminf(fmaxf(s, 1.f), 5.f);
  const float* dp = det + ((long)b << 19);
  long sp = ((long)i << 6) + j;
  int sidx = b * 8 + (c >> 2);
  float ll = tanhf((dp[((long)c << 12) + sp] - mll[sidx]) * rll[sidx] * gll[c] + bll[c]) * s;
  int hc = c; sidx = b * 8 + hc / 12;
  float lh = tanhf((dp[((long)(32 + hc) << 12) + sp] - mhi[sidx]) * rhi[sidx] * ghi[hc] + bhi[hc]) * s;
  hc = 32 + c; sidx = b * 8 + hc / 12;
  float hl = tanhf((dp[((long)(32 + hc) << 12) + sp] - mhi[sidx]) * rhi[sidx] * ghi[hc] + bhi[hc]) * s;
  hc = 64 + c; sidx = b * 8 + hc / 12;
  float hh = tanhf((dp[((long)(32 + hc) << 12) + sp] - mhi[sidx]) * rhi[sidx] * ghi[hc] + bhi[hc]) * s;
  float x00 = (ll + lh + hl + hh) * 0.5f;
  float x01 = (ll - lh + hl - hh) * 0.5f;
  float x10 = (ll + lh - hl - hh) * 0.5f;
  float x11 = (ll - lh - hl + hh) * 0.5f;
  float* rp = rec + (((long)b * 32 + c) << 14) + ((long)i << 8) + (j << 1);
  rp[0] = x00; rp[1] = x01; rp[128] = x10; rp[129] = x11;
}

// ============================================================================
// skip_up_raw = W_adj (128x32) @ rec
// ============================================================================
__global__ __launch_bounds__(256) void adj_k(const float* __restrict__ rec,
                                             const float* __restrict__ Wadj,
                                             float* __restrict__ out) {
  __shared__ float ls[32][256];
  int n0 = blockIdx.x << 8;
  int o0 = blockIdx.y << 4;
  int b = blockIdx.z;
  int t = threadIdx.x;
  for (int idx = t; idx < 32 * 256; idx += 256) {
    int c = idx >> 8, n = idx & 255;
    ls[c][n] = rec[(((long)b * 32 + c) << 14) + n0 + n];
  }
  __syncthreads();
  float acc[16];
#pragma unroll
  for (int i = 0; i < 16; i++) acc[i] = 0.f;
  for (int c = 0; c < 32; c++) {
    float v = ls[c][t];
#pragma unroll
    for (int i = 0; i < 16; i++) acc[i] += v * Wadj[(o0 + i) * 32 + c];
  }
#pragma unroll
  for (int i = 0; i < 16; i++)
    out[(((long)b * 128 + o0 + i) << 14) + n0 + t] = acc[i];
}

// ============================================================================
// GN apply. mode 0: plain, 1: relu, 2: silu then += add
// ============================================================================
__global__ void gn_apply_k(float* __restrict__ x, const float* __restrict__ mean,
                           const float* __restrict__ rstd, const float* __restrict__ gamma,
                           const float* __restrict__ beta, const float* __restrict__ add,
                           int mode) {
  long idx = ((long)blockIdx.x << 8) + threadIdx.x;
  int ch = (int)((idx >> 14) & 127);
  int b = (int)(idx >> 21);
  int s = b * 8 + (ch >> 4);
  float v = (x[idx] - mean[s]) * rstd[s] * gamma[ch] + beta[ch];
  if (mode == 1) v = fmaxf(v, 0.f);
  else if (mode == 2) { v = v / (1.f + expf(-v)); v += add[idx]; }
  x[idx] = v;
}

// BN apply + relu (+ optional add), in place
__global__ void bn_apply_k(float* __restrict__ x, const float* __restrict__ mean,
                           const float* __restrict__ rstd, const float* __restrict__ gamma,
                           const float* __restrict__ beta, const float* __restrict__ add) {
  long idx = ((long)blockIdx.x << 8) + threadIdx.x;
  int ch = (int)((idx >> 14) & 127);
  float v = fmaxf((x[idx] - mean[ch]) * rstd[ch] * gamma[ch] + beta[ch], 0.f);
  if (add) v += add[idx];
  x[idx] = v;
}

// ============================================================================
// column sum over N=16384
// ============================================================================
__global__ void colsum_k(const float* __restrict__ x, float* __restrict__ S) {
  int bc = blockIdx.x;
  const float* p = x + ((long)bc << 14);
  float a = 0.f;
  for (int i = threadIdx.x; i < 16384; i += 256) a += p[i];
  __shared__ float red[256];
  red[threadIdx.x] = a;
  __syncthreads();
  for (int off = 128; off > 0; off >>= 1) {
    if (threadIdx.x < off) red[threadIdx.x] += red[threadIdx.x + off];
    __syncthreads();
  }
  if (threadIdx.x == 0) S[bc] = red[0];
}

// ============================================================================
// Gram: G[p,b,c,c'] = sum_n merged[b,c,n]*feats[p][b,c',n]
// ============================================================================
__global__ __launch_bounds__(256) void gram_k(const float* __restrict__ merged,
                                              const float* __restrict__ f0,
                                              const float* __restrict__ f1,
                                              const float* __restrict__ f2,
                                              float* __restrict__ G) {
  int p = blockIdx.y, b = blockIdx.z;
  const float* fp = (p == 0) ? f0 : ((p == 1) ? f1 : f2);
  const float* mb = merged + ((long)b << 21);
  const float* fb = fp + ((long)b << 21);
  int n0 = blockIdx.x << 9;
  __shared__ float Am[128][17], Bm[128][17];
  int t = threadIdx.x;
  int tc = t >> 4, tcp = t & 15;
  float acc[8][8];
#pragma unroll
  for (int i = 0; i < 8; i++)
#pragma unroll
    for (int j = 0; j < 8; j++) acc[i][j] = 0.f;
  for (int ks = 0; ks < 32; ks++) {
    int nb = n0 + (ks << 4);
    for (int idx = t; idx < 2048; idx += 256) {
      int c = idx >> 4, k = idx & 15;
      Am[c][k] = mb[((long)c << 14) + nb + k];
      Bm[c][k] = fb[((long)c << 14) + nb + k];
    }
    __syncthreads();
    for (int k = 0; k < 16; k++) {
      float av[8], bv2[8];
#pragma unroll
      for (int i = 0; i < 8; i++) av[i] = Am[tc * 8 + i][k];
#pragma unroll
      for (int j = 0; j < 8; j++) bv2[j] = Bm[tcp * 8 + j][k];
#pragma unroll
      for (int i = 0; i < 8; i++)
#pragma unroll
        for (int j = 0; j < 8; j++) acc[i][j] += av[i] * bv2[j];
    }
    __syncthreads();
  }
  float* Gp = G + ((long)(p * 4 + b) << 14);
#pragma unroll
  for (int i = 0; i < 8; i++)
#pragma unroll
    for (int j = 0; j < 8; j++)
      atomicAdd(&Gp[(tc * 8 + i) * 128 + tcp * 8 + j], acc[i][j]);
}

// ============================================================================
// attention logits from Gram + softmax
// ============================================================================
__global__ __launch_bounds__(256) void attn_k(const float* __restrict__ G,
                                              const float* __restrict__ S1,
                                              const float* __restrict__ S2,
                                              const float* __restrict__ Wq,
                                              const float* __restrict__ bq,
                                              const float* __restrict__ Wk,
                                              const float* __restrict__ bk,
                                              float* __restrict__ attn) {
  int h = blockIdx.x, b = blockIdx.y, p = blockIdx.z;
  __shared__ float T[32][129];
  __shared__ float QS2[32], KS1[32];
  __shared__ float L[32][33];
  const float* Gpb = G + ((long)(p * 4 + b) << 14);
  const float* Wqp = Wq + p * 16384;
  const float* Wkp = Wk + p * 16384;
  int t = threadIdx.x;
  if (t < 32) {
    float a = 0.f;
    for (int c = 0; c < 128; c++) a += Wqp[(h * 32 + t) * 128 + c] * S2[b * 128 + c];
    QS2[t] = a;
  } else if (t < 64) {
    int e = t - 32;
    float a = 0.f;
    for (int c = 0; c < 128; c++) a += Wkp[(h * 32 + e) * 128 + c] * S1[(p * 4 + b) * 128 + c];
    KS1[e] = a;
  }
  __syncthreads();
  for (int ii = t; ii < 4096; ii += 256) {
    int d = ii >> 7, cp = ii & 127;
    float a = 0.f;
    for (int c = 0; c < 128; c++) a += Wqp[(h * 32 + d) * 128 + c] * Gpb[c * 128 + cp];
    T[d][cp] = a;
  }
  __syncthreads();
  const float scale = 0.17677669529663687f;
  for (int ii = t; ii < 1024; ii += 256) {
    int d = ii >> 5, e = ii & 31;
    float a = 0.f;
    for (int cp = 0; cp < 128; cp++) a += T[d][cp] * Wkp[(h * 32 + e) * 128 + cp];
    float bqv = bq[p * 128 + h * 32 + d], bkv = bk[p * 128 + h * 32 + e];
    a += bqv * KS1[e] + bkv * QS2[d] + 16384.f * bqv * bkv;
    L[d][e] = a * scale;
  }
  __syncthreads();
  if (t < 32) {
    float mx = -1e30f;
    for (int e = 0; e < 32; e++) mx = fmaxf(mx, L[t][e]);
    float sum = 0.f;
    for (int e = 0; e < 32; e++) { float ev = expf(L[t][e] - mx); L[t][e] = ev; sum += ev; }
    float inv = 1.f / sum;
    float* ap = attn + ((((long)(p * 4 + b)) * 4 + h) * 32 + t) * 32;
    for (int e = 0; e < 32; e++) ap[e] = L[t][e] * inv;
  }
}

// ============================================================================
// M + cbias
// ============================================================================
__global__ void m_k(const float* __restrict__ Wf, const float* __restrict__ attn,
                    const float* __restrict__ bv, float* __restrict__ M,
                    float* __restrict__ cbias) {
  int o = blockIdx.x, b = blockIdx.y, p = blockIdx.z;
  int ap = threadIdx.x;
  int h = ap >> 5, e = ap & 31;
  const float* at = attn + (((long)(p * 4 + b)) * 4 + h) * 1024;
  const float* wrow = Wf + o * 384 + p * 128 + h * 32;
  float acc = 0.f;
  for (int d = 0; d < 32; d++) acc += wrow[d] * at[d * 32 + e];
  M[(((long)(p * 4 + b)) * 128 + o) * 128 + ap] = acc;
  __shared__ float red[128];
  red[ap] = acc * bv[p * 128 + ap];
  __syncthreads();
  for (int off = 64; off > 0; off >>= 1) {
    if (ap < off) red[ap] += red[ap + off];
    __syncthreads();
  }
  if (ap == 0) atomicAdd(&cbias[b * 128 + o], red[0]);
}

__global__ void weff_k(const float* __restrict__ M, const float* __restrict__ Wv,
                       float* __restrict__ Weff) {
  int o = blockIdx.x, b = blockIdx.y, p = blockIdx.z, c = threadIdx.x;
  const float* mrow = M + (((long)(p * 4 + b)) * 128 + o) * 128;
  const float* wv = Wv + p * 16384;
  float acc = 0.f;
  for (int a = 0; a < 128; a++) acc += mrow[a] * wv[a * 128 + c];
  Weff[(((long)b * 128 + o) * 3 + p) * 128 + c] = acc;
}

// ============================================================================
// fused_pre = Weff @ feats + b_fuse + cbias
// ============================================================================
__global__ __launch_bounds__(256) void fuse_gemm_k(const float* __restrict__ Weff,
                                                   const float* __restrict__ f0,
                                                   const float* __restrict__ f1,
                                                   const float* __restrict__ f2,
                                                   const float* __restrict__ bf,
                                                   const float* __restrict__ cbias,
                                                   float* __restrict__ out) {
  int b = blockIdx.z;
  int o0 = blockIdx.y * 64;
  int n0 = blockIdx.x * 64;
  __shared__ float As[16][65], Bs[16][65];
  int t = threadIdx.x;
  int tn = t & 15, to = t >> 4;
  float acc[4][4];
#pragma unroll
  for (int i = 0; i < 4; i++)
#pragma unroll
    for (int j = 0; j < 4; j++) acc[i][j] = 0.f;
  for (int k0 = 0; k0 < 384; k0 += 16) {
    for (int idx = t; idx < 1024; idx += 256) {
      int o = idx >> 4, k = idx & 15;
      As[k][o] = Weff[((long)(b * 128 + o0 + o)) * 384 + k0 + k];
    }
    for (int idx = t; idx < 1024; idx += 256) {
      int k = idx >> 6, n = idx & 63;
      int c = k0 + k;
      const float* f = (c < 128) ? f0 : ((c < 256) ? f1 : f2);
      int cc = c & 127;
      Bs[k][n] = f[(((long)b * 128 + cc) << 14) + n0 + n];
    }
    __syncthreads();
    for (int k = 0; k < 16; k++) {
      float av[4], bvv[4];
#pragma unroll
      for (int i = 0; i < 4; i++) av[i] = As[k][to * 4 + i];
#pragma unroll
      for (int j = 0; j < 4; j++) bvv[j] = Bs[k][tn * 4 + j];
#pragma unroll
      for (int i = 0; i < 4; i++)
#pragma unroll
        for (int j = 0; j < 4; j++) acc[i][j] += av[i] * bvv[j];
    }
    __syncthreads();
  }
#pragma unroll
  for (int i = 0; i < 4; i++) {
    int o = o0 + to * 4 + i;
    float bias = bf[o] + cbias[b * 128 + o];
#pragma unroll
    for (int j = 0; j < 4; j++)
      out[(((long)b * 128 + o) << 14) + n0 + tn * 4 + j] = acc[i][j] + bias;
  }
}

// ============================================================================
extern "C" void kernel_launch(void* const* d_in, const int* in_sizes, int n_in,
                              void* d_out, int out_size, void* d_ws, size_t ws_size,
                              hipStream_t stream) {
  const float* x      = (const float*)d_in[0];
  const float* sdet   = (const float*)d_in[1];
  const float* sstru  = (const float*)d_in[2];
  const float* sglob  = (const float*)d_in[3];
  const float* W_up   = (const float*)d_in[4];
  const float* bnug   = (const float*)d_in[5];
  const float* bnub   = (const float*)d_in[6];
  const float* W_ll   = (const float*)d_in[7];
  const float* gllg   = (const float*)d_in[8];
  const float* gllb   = (const float*)d_in[9];
  const float* W_hi   = (const float*)d_in[10];
  const float* ghig   = (const float*)d_in[11];
  const float* ghib   = (const float*)d_in[12];
  const float* wsc    = (const float*)d_in[13];
  const float* W_adj  = (const float*)d_in[14];
  const float* gadjg  = (const float*)d_in[15];
  const float* gadjb  = (const float*)d_in[16];
  const float* Wq     = (const float*)d_in[17];
  const float* bq     = (const float*)d_in[18];
  const float* Wk     = (const float*)d_in[19];
  const float* bk     = (const float*)d_in[20];
  const float* Wv     = (const float*)d_in[21];
  const float* bv     = (const float*)d_in[22];
  const float* W_fu   = (const float*)d_in[23];
  const float* b_fu   = (const float*)d_in[24];
  const float* gfug   = (const float*)d_in[25];
  const float* gfub   = (const float*)d_in[26];
  const float* goug   = (const float*)d_in[27];
  const float* goub   = (const float*)d_in[28];
  const float* W_r1   = (const float*)d_in[29];
  const float* bn1g   = (const float*)d_in[30];
  const float* bn1b   = (const float*)d_in[31];
  const float* W_r2   = (const float*)d_in[32];
  const float* bn2g   = (const float*)d_in[33];
  const float* bn2b   = (const float*)d_in[34];
  float* out = (float*)d_out;

  float* ws = (float*)d_ws;
  size_t off = 0;
  auto alloc = [&](size_t n) { float* p = ws + off; off += n; return p; };
  float* bufA = alloc(8388608);   // fused_pre / att buffer (4,128,16384)
  float* bufB = alloc(8388608);   // conv_up out -> merged; later r1
  float* bufC = alloc(8388608);   // skip_up
  float* bufD = alloc(8388608);   // resized skip_global
  float* det  = alloc(2097152);   // (4,128,64,64)
  float* rec  = alloc(2097152);   // (4,32,128,128)
  unsigned short* xbf = (unsigned short*)alloc(8388608);  // bf16 NHWC conv inputs (16.7M u16)
  unsigned short* wpk_up = (unsigned short*)alloc(147456);
  unsigned short* wpk_r1 = (unsigned short*)alloc(73728);
  unsigned short* wpk_r2 = (unsigned short*)alloc(73728);
  unsigned short* wpk_dt = (unsigned short*)alloc(73728);
  float* Gm   = alloc(196608);
  float* S1b  = alloc(1536);
  float* S2b  = alloc(512);
  float* attb = alloc(49152);
  float* Mb   = alloc(196608);
  float* Wef  = alloc(196608);
  float* cb   = alloc(512);
  float* sums = alloc(1024);
  float* mLL = alloc(32); float* rLL = alloc(32);
  float* mHI = alloc(32); float* rHI = alloc(32);
  float* mS  = alloc(256); float* rS = alloc(256);

  const float s63 = 63.f / 127.f;

  // ---- weight prepack (bf16 [9][128][Cin])
  packw_k<<<1152, 256, 0, stream>>>(W_up, wpk_up, 128, 256, 0);
  packw_k<<<576, 256, 0, stream>>>(W_r1, wpk_r1, 128, 128, 0);
  packw_k<<<576, 256, 0, stream>>>(W_r2, wpk_r2, 128, 128, 0);
  packw_k<<<144, 256, 0, stream>>>(W_ll, wpk_dt, 32, 128, 0);
  packw_k<<<432, 256, 0, stream>>>(W_hi, wpk_dt, 96, 128, 32);

  // ---- detail branch: combined conv (Cout 128 = [ll|high]) via MFMA
  t_nhwc_k<<<dim3(64, 4, 4), 256, 0, stream>>>(sdet, xbf, 128, 4096);
  conv_mfma_k<64, 128, 2, 4><<<dim3(64, 4), 256, 0, stream>>>(xbf, wpk_dt, det, 64);
  hipMemsetAsync(sums, 0, 64 * sizeof(float), stream);
  gn_sums_k<<<dim3(32, 4), 256, 0, stream>>>(det, sums, 128, 0, 4, 4096, 8);
  stats_fin_k<<<1, 64, 0, stream>>>(sums, mLL, rLL, 32, 1.f / 16384.f);
  hipMemsetAsync(sums, 0, 64 * sizeof(float), stream);
  gn_sums_k<<<dim3(32, 8), 256, 0, stream>>>(det, sums, 128, 32, 12, 4096, 8);
  stats_fin_k<<<1, 64, 0, stream>>>(sums, mHI, rHI, 32, 1.f / 49152.f);
  idwt_k<<<2048, 256, 0, stream>>>(det, mLL, rLL, gllg, gllb, mHI, rHI, ghig, ghib, wsc, rec);

  // ---- skip_up = relu(GN(W_adj @ rec))
  adj_k<<<dim3(64, 8, 4), 256, 0, stream>>>(rec, W_adj, bufC);
  hipMemsetAsync(sums, 0, 64 * sizeof(float), stream);
  gn_sums_k<<<dim3(32, 16), 256, 0, stream>>>(bufC, sums, 128, 0, 16, 16384, 8);
  stats_fin_k<<<1, 64, 0, stream>>>(sums, mS, rS, 32, 1.f / 262144.f);
  gn_apply_k<<<32768, 256, 0, stream>>>(bufC, mS, rS, gadjg, gadjb, nullptr, 1);

  // ---- xu = resize(x) direct to bf16 NHWC; conv_up via MFMA; merged = relu(BN)+skip
  resize_bf_k<<<8192, 256, 0, stream>>>(x, xbf, 256, 64, 64, 128, 128, s63);
  conv_mfma_k<128, 256, 4, 4><<<dim3(128, 4), 256, 0, stream>>>(xbf, wpk_up, bufB, 128);
  hipMemsetAsync(sums, 0, 256 * sizeof(float), stream);
  bn_sums_k<<<dim3(128, 16), 256, 0, stream>>>(bufB, sums, 128);
  stats_fin_k<<<1, 128, 0, stream>>>(sums, mS, rS, 128, 1.f / 65536.f);
  bn_apply_k<<<32768, 256, 0, stream>>>(bufB, mS, rS, bnug, bnub, bufC);

  // ---- feats[2] = resize(skip_global) fp32
  resize_k<<<32768, 256, 0, stream>>>(sglob, bufD, 128, 64, 64, 128, 128, s63, s63);

  // ---- attention via Gram matrices
  colsum_k<<<512, 256, 0, stream>>>(bufB, S2b);
  colsum_k<<<512, 256, 0, stream>>>(bufC, S1b);
  colsum_k<<<512, 256, 0, stream>>>(sstru, S1b + 512);
  colsum_k<<<512, 256, 0, stream>>>(bufD, S1b + 1024);
  hipMemsetAsync(Gm, 0, 196608 * sizeof(float), stream);
  gram_k<<<dim3(32, 3, 4), 256, 0, stream>>>(bufB, bufC, sstru, bufD, Gm);
  attn_k<<<dim3(4, 4, 3), 256, 0, stream>>>(Gm, S1b, S2b, Wq, bq, Wk, bk, attb);

  // ---- collapse attn@v + concat + W_fuse into per-batch 384->128 GEMM
  hipMemsetAsync(cb, 0, 512 * sizeof(float), stream);
  m_k<<<dim3(128, 4, 3), 128, 0, stream>>>(W_fu, attb, bv, Mb, cb);
  weff_k<<<dim3(128, 4, 3), 128, 0, stream>>>(Mb, Wv, Wef);
  fuse_gemm_k<<<dim3(256, 2, 4), 256, 0, stream>>>(Wef, bufC, sstru, bufD, b_fu, cb, bufA);

  // ---- fused = silu(GN(fused_pre)); att_in = merged + fused (in place bufA)
  hipMemsetAsync(sums, 0, 64 * sizeof(float), stream);
  gn_sums_k<<<dim3(32, 16), 256, 0, stream>>>(bufA, sums, 128, 0, 16, 16384, 8);
  stats_fin_k<<<1, 64, 0, stream>>>(sums, mS, rS, 32, 1.f / 262144.f);
  gn_apply_k<<<32768, 256, 0, stream>>>(bufA, mS, rS, gfug, gfub, bufB, 2);

  // ---- att_out = GN(att_in)
  hipMemsetAsync(sums, 0, 64 * sizeof(float), stream);
  gn_sums_k<<<dim3(32, 16), 256, 0, stream>>>(bufA, sums, 128, 0, 16, 16384, 8);
  stats_fin_k<<<1, 64, 0, stream>>>(sums, mS, rS, 32, 1.f / 262144.f);
  gn_apply_k<<<32768, 256, 0, stream>>>(bufA, mS, rS, goug, goub, nullptr, 0);

  // ---- r1 = relu(BN(conv(att_out, W_r1))) via MFMA
  t_nhwc_k<<<dim3(256, 4, 4), 256, 0, stream>>>(bufA, xbf, 128, 16384);
  conv_mfma_k<128, 128, 4, 4><<<dim3(128, 4), 256, 0, stream>>>(xbf, wpk_r1, bufB, 128);
  hipMemsetAsync(sums, 0, 256 * sizeof(float), stream);
  bn_sums_k<<<dim3(128, 16), 256, 0, stream>>>(bufB, sums, 128);
  stats_fin_k<<<1, 128, 0, stream>>>(sums, mS, rS, 128, 1.f / 65536.f);
  bn_apply_k<<<32768, 256, 0, stream>>>(bufB, mS, rS, bn1g, bn1b, nullptr);

  // ---- r2 = relu(BN(conv(r1, W_r2))) -> d_out
  t_nhwc_k<<<dim3(256, 4, 4), 256, 0, stream>>>(bufB, xbf, 128, 16384);
  conv_mfma_k<128, 128, 4, 4><<<dim3(128, 4), 256, 0, stream>>>(xbf, wpk_r2, out, 128);
  hipMemsetAsync(sums, 0, 256 * sizeof(float), stream);
  bn_sums_k<<<dim3(128, 16), 256, 0, stream>>>(out, sums, 128);
  stats_fin_k<<<1, 128, 0, stream>>>(sums, mS, rS, 128, 1.f / 65536.f);
  bn_apply_k<<<32768, 256, 0, stream>>>(out, mS, rS, bn2g, bn2b, nullptr);
}